// Round 15
// baseline (138.582 us; speedup 1.0000x reference)
//
#include <hip/hip_runtime.h>

// STGraphConstructor: adj[b] = tanh(relu(A_b A_b^T) + I), A_b = [5096 x 64] fp32.
// R15: R8 body verbatim; ordering = XCD-column-pinned tall-narrow fronts.
//  - Evidence: R8 (tall-narrow front, all rows x 13 col-slabs) = 109.2 beats
//    R14 (short-wide, 13 bands x all cols) = 132.5. Gradient: narrower+taller
//    wins. Dirty set = 4MB/XCD = exactly L2 => eviction order shapes the HBM
//    stream; narrow per-XCD column footprint = fewer DRAM page groups.
//  - This round: xcd = wid%8 owns col-slabs bj = xcd+8t (t=0..4); within a
//    (bj,b) pair, bi sweeps 0..39 consecutively => per-XCD front = one 512B
//    column slab x all rows. Col-panel also stays hot in that XCD's L2.
//  - Kernel body, numerics, launch_bounds identical to R8 (the champion).

#define NSP 5000
#define NTM 96
#define MM  5096
#define DD  64
#define BT  128
#define NTILE 40   // ceil(5096/128)

typedef __attribute__((ext_vector_type(8))) short short8;
typedef __attribute__((ext_vector_type(8))) unsigned short ushort8;
typedef __attribute__((ext_vector_type(4))) float f32x4;

__device__ __forceinline__ unsigned short bf16_rn(float x) {
  unsigned u = __float_as_uint(x);
  u += 0x7FFFu + ((u >> 16) & 1u);
  return (unsigned short)(u >> 16);
}
__device__ __forceinline__ float bf16_f32(unsigned short s) {
  return __uint_as_float(((unsigned)s) << 16);
}

// ---- prep: convert concat(sp,tm) [B][MM][DD] fp32 -> hi/lo bf16 panels ----
__global__ __launch_bounds__(256) void stg_prep_kernel(
    const float* __restrict__ sp, const float* __restrict__ tm,
    unsigned short* __restrict__ wsh, unsigned short* __restrict__ wsl) {
  const int tid = blockIdx.x * 256 + threadIdx.x;
  const int flat = tid * 8;
  const int b = flat / (MM * DD);
  const int rem = flat - b * (MM * DD);
  const int m = rem / DD;
  const int d = rem - m * DD;
  const float* src = (m < NSP)
      ? sp + ((size_t)b * NSP + m) * DD + d
      : tm + ((size_t)b * NTM + (m - NSP)) * DD + d;
  const float4* s4 = reinterpret_cast<const float4*>(src);
  float f[8];
  {
    float4 v0 = s4[0], v1 = s4[1];
    f[0]=v0.x; f[1]=v0.y; f[2]=v0.z; f[3]=v0.w;
    f[4]=v1.x; f[5]=v1.y; f[6]=v1.z; f[7]=v1.w;
  }
  ushort8 H, L;
  #pragma unroll
  for (int i = 0; i < 8; ++i) {
    const unsigned short hi = bf16_rn(f[i]);
    H[i] = hi;
    L[i] = bf16_rn(f[i] - bf16_f32(hi));
  }
  *reinterpret_cast<ushort8*>(wsh + flat) = H;
  *reinterpret_cast<ushort8*>(wsl + flat) = L;
}

// ---- main: 128x128 tile, LDS-staged pre-converted panels ----
__global__ __launch_bounds__(256, 2) void stg_adj_kernel(
    const unsigned short* __restrict__ wsh,
    const unsigned short* __restrict__ wsl,
    float* __restrict__ out) {
  __shared__ unsigned char lds[65536];   // 4 x 16KB: RH, RL, CH, CL

  // XCD-column-pinned decode: xcd owns bj = xcd + 8t; bi fastest within (bj,b)
  const int wid = blockIdx.x;
  const int x = wid & 7;           // XCD (empirical round-robin)
  const int u = wid >> 3;          // 0..799 per-XCD sequence
  const int bi = u % 40;
  const int t5 = (u / 40) % 5;
  const int b  = u / 200;
  const int bj = x + 8 * t5;

  const int t = threadIdx.x;
  const size_t pb = (size_t)b * MM * DD;

  // ---- staging: 4 components x 4 granules/thread, coalesced 16B loads ----
  #pragma unroll
  for (int comp = 0; comp < 4; ++comp) {
    const int tbase = (comp < 2 ? bi : bj) * BT;
    const unsigned short* src = ((comp & 1) ? wsl : wsh) + pb;
    unsigned char* dst = lds + comp * 16384;
    #pragma unroll
    for (int k = 0; k < 4; ++k) {
      const int G = t + k * 256;          // granule 0..1023
      const int row = G >> 3;             // 0..127
      const int g = G & 7;                // 16B granule within row
      int grow = tbase + row; grow = grow < MM ? grow : MM - 1;
      const ushort8 v = *reinterpret_cast<const ushort8*>(src + (size_t)grow * DD + g * 8);
      *reinterpret_cast<ushort8*>(dst + row * 128 + ((g ^ (row & 7)) << 4)) = v;
    }
  }
  __syncthreads();

  // ---- compute: each wave owns a 64x64 quadrant = 4x4 MFMA tiles ----
  const int lane = t & 63;
  const int wave = t >> 6;
  const int wr = (wave >> 1) << 6;
  const int wc = (wave & 1) << 6;
  const int lr = lane & 15;
  const int lg = lane >> 4;

  f32x4 acc[4][4];
  #pragma unroll
  for (int m = 0; m < 4; ++m)
    #pragma unroll
    for (int n = 0; n < 4; ++n)
      acc[m][n] = (f32x4){0.f, 0.f, 0.f, 0.f};

  #pragma unroll
  for (int ks = 0; ks < 2; ++ks) {
    short8 ah[4], al[4], ch[4], cl[4];
    #pragma unroll
    for (int m = 0; m < 4; ++m) {
      const int ra = wr + m * 16 + lr;    // local row in row-panel
      const unsigned ga = (unsigned)((lg + ks * 4) ^ (ra & 7)) << 4;
      ah[m] = *reinterpret_cast<short8*>(lds +         ra * 128 + ga);
      al[m] = *reinterpret_cast<short8*>(lds + 16384 + ra * 128 + ga);
      const int rc = wc + m * 16 + lr;    // local row in col-panel
      const unsigned gc_ = (unsigned)((lg + ks * 4) ^ (rc & 7)) << 4;
      ch[m] = *reinterpret_cast<short8*>(lds + 32768 + rc * 128 + gc_);
      cl[m] = *reinterpret_cast<short8*>(lds + 49152 + rc * 128 + gc_);
    }
    // swapped operands (R4-verified): lane holds row gr0+m*16+lr, cols gc0+n*16+lg*4+q
    #pragma unroll
    for (int m = 0; m < 4; ++m) {
      #pragma unroll
      for (int n = 0; n < 4; ++n) {
        acc[m][n] = __builtin_amdgcn_mfma_f32_16x16x32_bf16(ch[n], ah[m], acc[m][n], 0, 0, 0);
        acc[m][n] = __builtin_amdgcn_mfma_f32_16x16x32_bf16(ch[n], al[m], acc[m][n], 0, 0, 0);
        acc[m][n] = __builtin_amdgcn_mfma_f32_16x16x32_bf16(cl[n], ah[m], acc[m][n], 0, 0, 0);
      }
    }
  }

  // ---- epilogue: tanh(relu(x)+eye), direct float4 burst stores ----
  const size_t cbase = (size_t)b * MM * MM;
  const int gr0 = bi * BT + wr;
  const int gc0 = bj * BT + wc;
  #pragma unroll
  for (int m = 0; m < 4; ++m) {
    const int gr = gr0 + m * 16 + lr;
    if (gr < MM) {
      float* rowp = out + cbase + (size_t)gr * MM;
      #pragma unroll
      for (int n = 0; n < 4; ++n) {
        const int gc = gc0 + n * 16 + lg * 4;
        if (gc < MM) {   // gc, MM multiples of 4 => whole float4 in bounds
          f32x4 v;
          #pragma unroll
          for (int q = 0; q < 4; ++q) {
            float xv = fmaxf(acc[m][n][q], 0.f);
            xv += (gr == gc + q) ? 1.f : 0.f;
            const float e = __builtin_amdgcn_exp2f(xv * 2.8853900817779268f);
            v[q] = 1.f - 2.f * __builtin_amdgcn_rcpf(e + 1.f);
          }
          *reinterpret_cast<f32x4*>(rowp + gc) = v;
        }
      }
    }
  }
}

extern "C" void kernel_launch(void* const* d_in, const int* in_sizes, int n_in,
                              void* d_out, int out_size, void* d_ws, size_t ws_size,
                              hipStream_t stream) {
  const float* sp = (const float*)d_in[0];
  const float* tm = (const float*)d_in[1];
  float* out = (float*)d_out;
  const int B = in_sizes[0] / (NSP * DD);   // = 4
  unsigned short* wsh = (unsigned short*)d_ws;
  unsigned short* wsl = wsh + (size_t)B * MM * DD;

  const int prep_threads = B * MM * DD / 8;
  stg_prep_kernel<<<dim3(prep_threads / 256), dim3(256), 0, stream>>>(sp, tm, wsh, wsl);

  stg_adj_kernel<<<dim3(6400), dim3(256), 0, stream>>>(wsh, wsl, out);
}

// Round 16
// 110.974 us; speedup vs baseline: 1.2488x; 1.2488x over previous
//
#include <hip/hip_runtime.h>

// STGraphConstructor: adj[b] = tanh(relu(A_b A_b^T) + I), A_b = [5096 x 64] fp32.
// R16: R8 (champion, 109.2us) + global_load_lds width=16 staging.
//  - Ordering/coverage ledger closed: R8's default dispatch beats all 7 tested
//    write-stream structures; residency 2->5 blk/CU null. ~3.9 TB/s tile
//    writeback is invariant => stop optimizing stores.
//  - This round: kill the staging VGPR round-trip (guide common-mistake #1).
//    global_load_lds(16B): 64 async 1KB wave-instructions per block, LDS dest
//    linear, XOR-swizzle moved to the per-lane GLOBAL source address (m173
//    pattern — swizzle is row-local so source stays a valid per-lane addr).
//    LDS read side and everything else identical to R8.

#define NSP 5000
#define NTM 96
#define MM  5096
#define DD  64
#define BT  128
#define NTILE 40   // ceil(5096/128)

typedef __attribute__((ext_vector_type(8))) short short8;
typedef __attribute__((ext_vector_type(8))) unsigned short ushort8;
typedef __attribute__((ext_vector_type(4))) float f32x4;

typedef const __attribute__((address_space(1))) unsigned int GU32;
typedef __attribute__((address_space(3))) unsigned int LU32;

__device__ __forceinline__ unsigned short bf16_rn(float x) {
  unsigned u = __float_as_uint(x);
  u += 0x7FFFu + ((u >> 16) & 1u);
  return (unsigned short)(u >> 16);
}
__device__ __forceinline__ float bf16_f32(unsigned short s) {
  return __uint_as_float(((unsigned)s) << 16);
}

// ---- prep: convert concat(sp,tm) [B][MM][DD] fp32 -> hi/lo bf16 panels ----
__global__ __launch_bounds__(256) void stg_prep_kernel(
    const float* __restrict__ sp, const float* __restrict__ tm,
    unsigned short* __restrict__ wsh, unsigned short* __restrict__ wsl) {
  const int tid = blockIdx.x * 256 + threadIdx.x;
  const int flat = tid * 8;
  const int b = flat / (MM * DD);
  const int rem = flat - b * (MM * DD);
  const int m = rem / DD;
  const int d = rem - m * DD;
  const float* src = (m < NSP)
      ? sp + ((size_t)b * NSP + m) * DD + d
      : tm + ((size_t)b * NTM + (m - NSP)) * DD + d;
  const float4* s4 = reinterpret_cast<const float4*>(src);
  float f[8];
  {
    float4 v0 = s4[0], v1 = s4[1];
    f[0]=v0.x; f[1]=v0.y; f[2]=v0.z; f[3]=v0.w;
    f[4]=v1.x; f[5]=v1.y; f[6]=v1.z; f[7]=v1.w;
  }
  ushort8 H, L;
  #pragma unroll
  for (int i = 0; i < 8; ++i) {
    const unsigned short hi = bf16_rn(f[i]);
    H[i] = hi;
    L[i] = bf16_rn(f[i] - bf16_f32(hi));
  }
  *reinterpret_cast<ushort8*>(wsh + flat) = H;
  *reinterpret_cast<ushort8*>(wsl + flat) = L;
}

// ---- main: 128x128 tile, global_load_lds staging, R8 compute/epilogue ----
__global__ __launch_bounds__(256, 2) void stg_adj_kernel(
    const unsigned short* __restrict__ wsh,
    const unsigned short* __restrict__ wsl,
    float* __restrict__ out) {
  __shared__ unsigned char lds[65536];   // 4 x 16KB: RH, RL, CH, CL (linear dest)
  const int bi = blockIdx.x;
  const int bj = blockIdx.y;
  const int b  = blockIdx.z;
  const int t  = threadIdx.x;
  const int lane = t & 63;
  const int wave = t >> 6;

  const size_t pb = (size_t)b * MM * DD;
  const unsigned short* Xh = wsh + pb;
  const unsigned short* Xl = wsl + pb;

  // ---- staging: 16 async global_load_lds(16B) per wave, 64 total ----
  // Granule G = (wave*16 + j)*64 + lane; LDS dest = lds + G*16 (linear).
  // G -> comp = G>>10, row = (G&1023)>>3, g = G&7. LDS granule g of a row
  // holds SOURCE granule g^(row&7)  (XOR pre-applied on the global address).
  #pragma unroll
  for (int j = 0; j < 16; ++j) {
    const int Gbase = (wave * 16 + j) * 64;       // uniform per wave
    const int G = Gbase + lane;
    const int comp = G >> 10;
    const int rem = G & 1023;
    const int row = rem >> 3;
    const int g = rem & 7;
    const int tbase = (comp < 2 ? bi : bj) * BT;
    int grow = tbase + row; grow = grow < MM ? grow : MM - 1;
    const unsigned short* src = (comp & 1) ? Xl : Xh;
    const unsigned short* gaddr = src + (size_t)grow * DD + ((g ^ (row & 7)) << 3);
    __builtin_amdgcn_global_load_lds((GU32*)gaddr, (LU32*)(lds + Gbase * 16), 16, 0, 0);
  }
  __syncthreads();   // drains vmcnt -> staged data visible

  // ---- compute: each wave owns a 64x64 quadrant = 4x4 MFMA tiles ----
  const int wr = (wave >> 1) << 6;
  const int wc = (wave & 1) << 6;
  const int lr = lane & 15;
  const int lg = lane >> 4;

  f32x4 acc[4][4];
  #pragma unroll
  for (int m = 0; m < 4; ++m)
    #pragma unroll
    for (int n = 0; n < 4; ++n)
      acc[m][n] = (f32x4){0.f, 0.f, 0.f, 0.f};

  #pragma unroll
  for (int ks = 0; ks < 2; ++ks) {
    short8 ah[4], al[4], ch[4], cl[4];
    #pragma unroll
    for (int m = 0; m < 4; ++m) {
      const int ra = wr + m * 16 + lr;    // local row in row-panel
      const unsigned ga = (unsigned)((lg + ks * 4) ^ (ra & 7)) << 4;
      ah[m] = *reinterpret_cast<short8*>(lds +         ra * 128 + ga);
      al[m] = *reinterpret_cast<short8*>(lds + 16384 + ra * 128 + ga);
      const int rc = wc + m * 16 + lr;    // local row in col-panel
      const unsigned gc_ = (unsigned)((lg + ks * 4) ^ (rc & 7)) << 4;
      ch[m] = *reinterpret_cast<short8*>(lds + 32768 + rc * 128 + gc_);
      cl[m] = *reinterpret_cast<short8*>(lds + 49152 + rc * 128 + gc_);
    }
    // swapped operands (R4-verified): lane holds row gr0+m*16+lr, cols gc0+n*16+lg*4+q
    #pragma unroll
    for (int m = 0; m < 4; ++m) {
      #pragma unroll
      for (int n = 0; n < 4; ++n) {
        acc[m][n] = __builtin_amdgcn_mfma_f32_16x16x32_bf16(ch[n], ah[m], acc[m][n], 0, 0, 0);
        acc[m][n] = __builtin_amdgcn_mfma_f32_16x16x32_bf16(ch[n], al[m], acc[m][n], 0, 0, 0);
        acc[m][n] = __builtin_amdgcn_mfma_f32_16x16x32_bf16(cl[n], ah[m], acc[m][n], 0, 0, 0);
      }
    }
  }

  // ---- epilogue: tanh(relu(x)+eye), direct float4 burst stores ----
  const size_t cbase = (size_t)b * MM * MM;
  const int gr0 = bi * BT + wr;
  const int gc0 = bj * BT + wc;
  #pragma unroll
  for (int m = 0; m < 4; ++m) {
    const int gr = gr0 + m * 16 + lr;
    if (gr < MM) {
      float* rowp = out + cbase + (size_t)gr * MM;
      #pragma unroll
      for (int n = 0; n < 4; ++n) {
        const int gc = gc0 + n * 16 + lg * 4;
        if (gc < MM) {   // gc, MM multiples of 4 => whole float4 in bounds
          f32x4 v;
          #pragma unroll
          for (int q = 0; q < 4; ++q) {
            float xv = fmaxf(acc[m][n][q], 0.f);
            xv += (gr == gc + q) ? 1.f : 0.f;
            const float e = __builtin_amdgcn_exp2f(xv * 2.8853900817779268f);
            v[q] = 1.f - 2.f * __builtin_amdgcn_rcpf(e + 1.f);
          }
          *reinterpret_cast<f32x4*>(rowp + gc) = v;
        }
      }
    }
  }
}

extern "C" void kernel_launch(void* const* d_in, const int* in_sizes, int n_in,
                              void* d_out, int out_size, void* d_ws, size_t ws_size,
                              hipStream_t stream) {
  const float* sp = (const float*)d_in[0];
  const float* tm = (const float*)d_in[1];
  float* out = (float*)d_out;
  const int B = in_sizes[0] / (NSP * DD);   // = 4
  unsigned short* wsh = (unsigned short*)d_ws;
  unsigned short* wsl = wsh + (size_t)B * MM * DD;

  const int prep_threads = B * MM * DD / 8;
  stg_prep_kernel<<<dim3(prep_threads / 256), dim3(256), 0, stream>>>(sp, tm, wsh, wsl);

  dim3 grid(NTILE, NTILE, B);
  stg_adj_kernel<<<grid, dim3(256), 0, stream>>>(wsh, wsl, out);
}